// Round 10
// baseline (488.522 us; speedup 1.0000x reference)
//
#include <hip/hip_runtime.h>
#include <hip/hip_fp16.h>

#define CHUNK 1024

typedef _Float16 half8 __attribute__((ext_vector_type(8)));
typedef float floatx4 __attribute__((ext_vector_type(4)));
typedef unsigned int uintx4 __attribute__((ext_vector_type(4)));

__device__ __forceinline__ unsigned int pack2(float a, float b) {
    __half2 h = __floats2half2_rn(a, b);
    return *(unsigned int*)&h;
}
__device__ __forceinline__ float2 unpack2(unsigned int u) {
    __half2 h = *(__half2*)&u;
    return __half22float2(h);
}
__device__ __forceinline__ void nt_store16(void* p, half8 v) {
    __builtin_nontemporal_store(*(uintx4*)&v, (uintx4*)p);
}
__device__ __forceinline__ uintx4 nt_load16(const void* p) {
    return __builtin_nontemporal_load((const uintx4*)p);
}

// ===========================================================================
// rank + fp16-convert fused: r[e] = rank within src bucket (atomic histo),
// eah[e] = fp16(ea[e]). Single-use streams are non-temporal.
// ===========================================================================
__global__ __launch_bounds__(256) void rank_cvt(
    const int* __restrict__ ei, const float* __restrict__ ea,
    int* __restrict__ deg, unsigned short* __restrict__ r,
    _Float16* __restrict__ eah, int E)
{
    int e = blockIdx.x * 256 + threadIdx.x;
    if (e >= E) return;
    r[e] = (unsigned short)atomicAdd(&deg[ei[e]], 1);
    uintx4 u0 = nt_load16(ea + (size_t)e * 8);
    uintx4 u1 = nt_load16(ea + (size_t)e * 8 + 4);
    float4 a0 = *(float4*)&u0;
    float4 a1 = *(float4*)&u1;
    half8 h;
    h[0] = (_Float16)a0.x; h[1] = (_Float16)a0.y;
    h[2] = (_Float16)a0.z; h[3] = (_Float16)a0.w;
    h[4] = (_Float16)a1.x; h[5] = (_Float16)a1.y;
    h[6] = (_Float16)a1.z; h[7] = (_Float16)a1.w;
    nt_store16(eah + (size_t)e * 8, h);
}

__global__ __launch_bounds__(256) void scan_chunk_sums(
    const int* __restrict__ v, int* __restrict__ csum, int N)
{
    __shared__ int s[256];
    int base = blockIdx.x * CHUNK;
    int t = threadIdx.x;
    int acc = 0;
    #pragma unroll
    for (int i = 0; i < CHUNK / 256; ++i) {
        int idx = base + t + i * 256;
        if (idx < N) acc += v[idx];
    }
    s[t] = acc; __syncthreads();
    for (int o = 128; o > 0; o >>= 1) {
        if (t < o) s[t] += s[t + o];
        __syncthreads();
    }
    if (t == 0) csum[blockIdx.x] = s[0];
}

__global__ void scan_chunk_off(
    const int* __restrict__ csum, int* __restrict__ coff, int nch)
{
    if (threadIdx.x == 0 && blockIdx.x == 0) {
        int acc = 0;
        for (int i = 0; i < nch; ++i) { coff[i] = acc; acc += csum[i]; }
    }
}

__global__ __launch_bounds__(256) void scan_within_excl(
    const int* __restrict__ deg, int* __restrict__ pos,
    const int* __restrict__ coff, int N)
{
    __shared__ int s[256];
    int t = threadIdx.x;
    int base = blockIdx.x * CHUNK + t * 4;
    int v0 = 0, v1 = 0, v2 = 0, v3 = 0;
    if (base + 0 < N) v0 = deg[base + 0];
    if (base + 1 < N) v1 = deg[base + 1];
    if (base + 2 < N) v2 = deg[base + 2];
    if (base + 3 < N) v3 = deg[base + 3];
    s[t] = v0 + v1 + v2 + v3;
    __syncthreads();
    for (int o = 1; o < 256; o <<= 1) {
        int add = (t >= o) ? s[t - o] : 0;
        __syncthreads();
        s[t] += add;
        __syncthreads();
    }
    int run = coff[blockIdx.x] + (t > 0 ? s[t - 1] : 0);
    if (base + 0 < N) pos[base + 0] = run; run += v0;
    if (base + 1 < N) pos[base + 1] = run; run += v1;
    if (base + 2 < N) pos[base + 2] = run; run += v2;
    if (base + 3 < N) pos[base + 3] = run;
}

// ===========================================================================
// MFMA edge-MLP: one 64-edge macro-tile per wave (4 independent 16x16 MFMA
// tiles); scattered output stores are NON-TEMPORAL (bypass L2 so the input
// streams stay resident). mlp1 also materializes p[e] for mlp2 to stream.
//   16x16x32 layouts: A[m=lane&15][k=8q+j], B[k=8q+j][n=lane&15],
//   C/D: col=lane&15, row=4q+reg.
// ===========================================================================
__global__ __launch_bounds__(256) void edge_mlp1(
    const float* __restrict__ x,          // [N,4]
    const int*   __restrict__ ei,         // [2,E]
    const _Float16* __restrict__ eah,     // [E,8] fp16
    const int*   __restrict__ pos,
    const unsigned short* __restrict__ r,
    int* __restrict__ pout,               // [E] CSR slot per edge (for mlp2)
    const float* __restrict__ w1, const float* __restrict__ b1,  // 16x16
    const float* __restrict__ w2, const float* __restrict__ b2,  // 16x16
    _Float16* __restrict__ m2h,           // [E,16] CSR-ordered
    int E)
{
    __shared__ _Float16 itm[4][4][16][24];   // [wave][tile][row][ch+pad]
    int tid = threadIdx.x;
    int w = tid >> 6, lane = tid & 63;
    int e16 = lane & 15, q = lane >> 4;
    int ntiles = (E + 63) >> 6;
    int tile = blockIdx.x * 4 + w;
    if (tile >= ntiles) return;
    int ebase = tile << 6;
    int e = ebase + lane;

    int s_l = 0, d_l = 0, p_l = 0;
    if (e < E) {
        s_l = ei[e];
        d_l = ei[E + e];
        p_l = pos[s_l] + (int)r[e];
        __builtin_nontemporal_store(p_l, pout + e);
    }

    half8 B1, B2;
    #pragma unroll
    for (int j = 0; j < 8; ++j) { B1[j] = (_Float16)0.f; B2[j] = (_Float16)0.f; }
    if (q < 2) {
        #pragma unroll
        for (int j = 0; j < 8; ++j) {
            B1[j] = (_Float16)w1[(8 * q + j) * 16 + e16];
            B2[j] = (_Float16)w2[(8 * q + j) * 16 + e16];
        }
    }
    float b1c = b1[e16], b2c = b2[e16];

    half8 A[4];
    #pragma unroll
    for (int t = 0; t < 4; ++t) {
        int st = __shfl(s_l, 16 * t + e16, 64);
        int dt = __shfl(d_l, 16 * t + e16, 64);
        half8 a;
        #pragma unroll
        for (int j = 0; j < 8; ++j) a[j] = (_Float16)0.f;
        int et = ebase + 16 * t + e16;
        if (q == 0 && et < E) {
            float4 xs = *(const float4*)(x + (size_t)st * 4);
            float4 xd = *(const float4*)(x + (size_t)dt * 4);
            a[0] = (_Float16)xs.x; a[1] = (_Float16)xs.y;
            a[2] = (_Float16)xs.z; a[3] = (_Float16)xs.w;
            a[4] = (_Float16)xd.x; a[5] = (_Float16)xd.y;
            a[6] = (_Float16)xd.z; a[7] = (_Float16)xd.w;
        } else if (q == 1 && et < E) {
            a = *(const half8*)(eah + (size_t)et * 8);
        }
        A[t] = a;
    }

    floatx4 C[4];
    #pragma unroll
    for (int t = 0; t < 4; ++t) {
        floatx4 c = {b1c, b1c, b1c, b1c};
        C[t] = __builtin_amdgcn_mfma_f32_16x16x32_f16(A[t], B1, c, 0, 0, 0);
    }
    #pragma unroll
    for (int t = 0; t < 4; ++t)
        #pragma unroll
        for (int i = 0; i < 4; ++i)
            itm[w][t][4 * q + i][e16] = (_Float16)fmaxf(C[t][i], 0.0f);
    __builtin_amdgcn_wave_barrier();

    half8 A2[4];
    #pragma unroll
    for (int t = 0; t < 4; ++t) {
        half8 a;
        #pragma unroll
        for (int j = 0; j < 8; ++j) a[j] = (_Float16)0.f;
        if (q < 2) a = *(const half8*)&itm[w][t][e16][8 * q];
        A2[t] = a;
    }
    __builtin_amdgcn_wave_barrier();
    floatx4 C2[4];
    #pragma unroll
    for (int t = 0; t < 4; ++t) {
        floatx4 c = {b2c, b2c, b2c, b2c};
        C2[t] = __builtin_amdgcn_mfma_f32_16x16x32_f16(A2[t], B2, c, 0, 0, 0);
    }
    #pragma unroll
    for (int t = 0; t < 4; ++t)
        #pragma unroll
        for (int i = 0; i < 4; ++i)
            itm[w][t][4 * q + i][e16] = (_Float16)C2[t][i];
    __builtin_amdgcn_wave_barrier();

    if (e < E) {
        half8 lo = *(const half8*)&itm[w][q][e16][0];
        half8 hi = *(const half8*)&itm[w][q][e16][8];
        nt_store16(m2h + (size_t)p_l * 16,     lo);
        nt_store16(m2h + (size_t)p_l * 16 + 8, hi);
    }
}

__global__ __launch_bounds__(256) void edge_mlp2(
    const float* __restrict__ hw_s,            // [N,16] fp32 (cb1 folded)
    const unsigned short* __restrict__ hw_dh,  // [N,16] fp16
    const int*   __restrict__ ei,
    const _Float16* __restrict__ eah,
    const int*   __restrict__ p,               // [E] precomputed CSR slots
    const float* __restrict__ w1,              // [40,16] rows 32:40 used
    const float* __restrict__ w2, const float* __restrict__ b2,
    _Float16* __restrict__ m2h, int E)
{
    __shared__ _Float16 itm[4][4][16][24];
    int tid = threadIdx.x;
    int w = tid >> 6, lane = tid & 63;
    int e16 = lane & 15, q = lane >> 4;
    const __half* hwd = (const __half*)hw_dh;
    int ntiles = (E + 63) >> 6;
    int tile = blockIdx.x * 4 + w;
    if (tile >= ntiles) return;
    int ebase = tile << 6;
    int e = ebase + lane;

    int s_l = 0, d_l = 0, p_l = 0;
    if (e < E) {
        s_l = ei[e];
        d_l = ei[E + e];
        p_l = p[e];
    }

    half8 B1, B2;
    #pragma unroll
    for (int j = 0; j < 8; ++j) { B1[j] = (_Float16)0.f; B2[j] = (_Float16)0.f; }
    if (q == 0) {
        #pragma unroll
        for (int j = 0; j < 8; ++j)
            B1[j] = (_Float16)w1[(32 + j) * 16 + e16];
    }
    if (q < 2) {
        #pragma unroll
        for (int j = 0; j < 8; ++j)
            B2[j] = (_Float16)w2[(8 * q + j) * 16 + e16];
    }
    float b2c = b2[e16];

    half8 A[4];
    #pragma unroll
    for (int t = 0; t < 4; ++t) {
        half8 a;
        #pragma unroll
        for (int j = 0; j < 8; ++j) a[j] = (_Float16)0.f;
        int et = ebase + 16 * t + e16;
        if (q == 0 && et < E)
            a = *(const half8*)(eah + (size_t)et * 8);
        A[t] = a;
    }

    floatx4 C[4];
    #pragma unroll
    for (int t = 0; t < 4; ++t) {
        floatx4 c;
        #pragma unroll
        for (int i = 0; i < 4; ++i) {
            int li = 16 * t + 4 * q + i;
            int s = __shfl(s_l, li, 64);
            int d = __shfl(d_l, li, 64);
            int rr = ebase + li;
            float v = 0.0f;
            if (rr < E) {
                v = hw_s[(size_t)s * 16 + e16]
                  + __half2float(hwd[(size_t)d * 16 + e16]);
            }
            c[i] = v;
        }
        C[t] = __builtin_amdgcn_mfma_f32_16x16x32_f16(A[t], B1, c, 0, 0, 0);
    }
    #pragma unroll
    for (int t = 0; t < 4; ++t)
        #pragma unroll
        for (int i = 0; i < 4; ++i)
            itm[w][t][4 * q + i][e16] = (_Float16)fmaxf(C[t][i], 0.0f);
    __builtin_amdgcn_wave_barrier();

    half8 A2[4];
    #pragma unroll
    for (int t = 0; t < 4; ++t) {
        half8 a;
        #pragma unroll
        for (int j = 0; j < 8; ++j) a[j] = (_Float16)0.f;
        if (q < 2) a = *(const half8*)&itm[w][t][e16][8 * q];
        A2[t] = a;
    }
    __builtin_amdgcn_wave_barrier();
    floatx4 C2[4];
    #pragma unroll
    for (int t = 0; t < 4; ++t) {
        floatx4 c = {b2c, b2c, b2c, b2c};
        C2[t] = __builtin_amdgcn_mfma_f32_16x16x32_f16(A2[t], B2, c, 0, 0, 0);
    }
    #pragma unroll
    for (int t = 0; t < 4; ++t)
        #pragma unroll
        for (int i = 0; i < 4; ++i)
            itm[w][t][4 * q + i][e16] = (_Float16)C2[t][i];
    __builtin_amdgcn_wave_barrier();

    if (e < E) {
        half8 lo = *(const half8*)&itm[w][q][e16][0];
        half8 hi = *(const half8*)&itm[w][q][e16][8];
        nt_store16(m2h + (size_t)p_l * 16,     lo);
        nt_store16(m2h + (size_t)p_l * 16 + 8, hi);
    }
}

// ===========================================================================
// Streaming segment-max kernels (8 lanes/node) + fused epilogues.
// m2h reads are non-temporal (single-use 51 MB stream).
// ===========================================================================
__global__ __launch_bounds__(256) void segmax1_hw(
    const _Float16* __restrict__ m2h, const int* __restrict__ pos,
    const float* __restrict__ cw1, const float* __restrict__ cb1,
    float* __restrict__ hw_s, unsigned short* __restrict__ hw_dh,
    int N, int E)
{
    int tid = threadIdx.x;
    int n = blockIdx.x * 32 + (tid >> 3);
    if (n >= N) return;
    int g = tid & 7;
    int start = pos[n];
    int end = (n + 1 < N) ? pos[n + 1] : E;

    float acc[16];
    #pragma unroll
    for (int j = 0; j < 16; ++j) acc[j] = 0.0f;

    for (int k = start + g; k < end; k += 8) {
        uintx4 u0 = nt_load16(m2h + (size_t)k * 16);
        uintx4 u1 = nt_load16(m2h + (size_t)k * 16 + 8);
        float2 f;
        f = unpack2(u0.x); acc[0]  = fmaxf(acc[0],  f.x); acc[1]  = fmaxf(acc[1],  f.y);
        f = unpack2(u0.y); acc[2]  = fmaxf(acc[2],  f.x); acc[3]  = fmaxf(acc[3],  f.y);
        f = unpack2(u0.z); acc[4]  = fmaxf(acc[4],  f.x); acc[5]  = fmaxf(acc[5],  f.y);
        f = unpack2(u0.w); acc[6]  = fmaxf(acc[6],  f.x); acc[7]  = fmaxf(acc[7],  f.y);
        f = unpack2(u1.x); acc[8]  = fmaxf(acc[8],  f.x); acc[9]  = fmaxf(acc[9],  f.y);
        f = unpack2(u1.y); acc[10] = fmaxf(acc[10], f.x); acc[11] = fmaxf(acc[11], f.y);
        f = unpack2(u1.z); acc[12] = fmaxf(acc[12], f.x); acc[13] = fmaxf(acc[13], f.y);
        f = unpack2(u1.w); acc[14] = fmaxf(acc[14], f.x); acc[15] = fmaxf(acc[15], f.y);
    }
    #pragma unroll
    for (int mask = 1; mask < 8; mask <<= 1) {
        #pragma unroll
        for (int j = 0; j < 16; ++j)
            acc[j] = fmaxf(acc[j], __shfl_xor(acc[j], mask, 64));
    }

    int j0 = 2 * g, j1 = 2 * g + 1;
    float hs0 = cb1[j0], hs1 = cb1[j1], hd0 = 0.0f, hd1 = 0.0f;
    #pragma unroll
    for (int k = 0; k < 16; ++k) {
        float ak = acc[k];
        hs0 = fmaf(ak, cw1[k * 16 + j0], hs0);
        hs1 = fmaf(ak, cw1[k * 16 + j1], hs1);
        hd0 = fmaf(ak, cw1[(16 + k) * 16 + j0], hd0);
        hd1 = fmaf(ak, cw1[(16 + k) * 16 + j1], hd1);
    }
    *(float2*)(hw_s + (size_t)n * 16 + j0) = make_float2(hs0, hs1);
    ((unsigned int*)hw_dh)[(size_t)n * 8 + g] = pack2(hd0, hd1);
}

__global__ __launch_bounds__(256) void segmax2_head(
    const _Float16* __restrict__ m2h, const int* __restrict__ pos,
    const float* __restrict__ l1w, const float* __restrict__ l1b,
    const float* __restrict__ l2w, const float* __restrict__ l2b,
    float* __restrict__ out, int N, int E)
{
    int tid = threadIdx.x;
    int n = blockIdx.x * 32 + (tid >> 3);
    if (n >= N) return;
    int g = tid & 7;
    int start = pos[n];
    int end = (n + 1 < N) ? pos[n + 1] : E;

    float acc[16];
    #pragma unroll
    for (int j = 0; j < 16; ++j) acc[j] = 0.0f;

    for (int k = start + g; k < end; k += 8) {
        uintx4 u0 = nt_load16(m2h + (size_t)k * 16);
        uintx4 u1 = nt_load16(m2h + (size_t)k * 16 + 8);
        float2 f;
        f = unpack2(u0.x); acc[0]  = fmaxf(acc[0],  f.x); acc[1]  = fmaxf(acc[1],  f.y);
        f = unpack2(u0.y); acc[2]  = fmaxf(acc[2],  f.x); acc[3]  = fmaxf(acc[3],  f.y);
        f = unpack2(u0.z); acc[4]  = fmaxf(acc[4],  f.x); acc[5]  = fmaxf(acc[5],  f.y);
        f = unpack2(u0.w); acc[6]  = fmaxf(acc[6],  f.x); acc[7]  = fmaxf(acc[7],  f.y);
        f = unpack2(u1.x); acc[8]  = fmaxf(acc[8],  f.x); acc[9]  = fmaxf(acc[9],  f.y);
        f = unpack2(u1.y); acc[10] = fmaxf(acc[10], f.x); acc[11] = fmaxf(acc[11], f.y);
        f = unpack2(u1.z); acc[12] = fmaxf(acc[12], f.x); acc[13] = fmaxf(acc[13], f.y);
        f = unpack2(u1.w); acc[14] = fmaxf(acc[14], f.x); acc[15] = fmaxf(acc[15], f.y);
    }
    #pragma unroll
    for (int mask = 1; mask < 8; mask <<= 1) {
        #pragma unroll
        for (int j = 0; j < 16; ++j)
            acc[j] = fmaxf(acc[j], __shfl_xor(acc[j], mask, 64));
    }

    float t2[16];
    #pragma unroll
    for (int j = 0; j < 16; ++j) t2[j] = l1b[j];
    #pragma unroll
    for (int kk = 0; kk < 16; ++kk) {
        float ak = acc[kk];
        #pragma unroll
        for (int j = 0; j < 16; ++j) t2[j] = fmaf(ak, l1w[kk * 16 + j], t2[j]);
    }
    float r2 = l2b[0];
    #pragma unroll
    for (int j = 0; j < 16; ++j) r2 = fmaf(fmaxf(t2[j], 0.0f), l2w[j], r2);
    if (g == 0) out[n] = r2;
}

// ===========================================================================
extern "C" void kernel_launch(void* const* d_in, const int* in_sizes, int n_in,
                              void* d_out, int out_size, void* d_ws, size_t ws_size,
                              hipStream_t stream)
{
    const float* x     = (const float*)d_in[0];
    const int*   ei    = (const int*)  d_in[1];
    const float* ea    = (const float*)d_in[2];
    const float* c1_w1 = (const float*)d_in[3];
    const float* c1_b1 = (const float*)d_in[4];
    const float* c1_w2 = (const float*)d_in[5];
    const float* c1_b2 = (const float*)d_in[6];
    const float* c2_w1 = (const float*)d_in[7];
    const float* c2_b1 = (const float*)d_in[8];
    const float* c2_w2 = (const float*)d_in[9];
    const float* c2_b2 = (const float*)d_in[10];
    const float* l1_w  = (const float*)d_in[11];
    const float* l1_b  = (const float*)d_in[12];
    const float* l2_w  = (const float*)d_in[13];
    const float* l2_b  = (const float*)d_in[14];
    float* out = (float*)d_out;

    const int N = in_sizes[0] / 4;   // 100000
    const int E = in_sizes[2] / 8;   // 1600000
    const int nch = (N + CHUNK - 1) / CHUNK;

    const int BLK = 256;
    const int egrid = (E + BLK - 1) / BLK;
    const int ggrid = (N + 31) / 32;
    const int ntiles64 = (E + 63) >> 6;
    const int mgrid = (ntiles64 + 3) / 4;     // one 64-edge tile per wave

    size_t szN16f = (size_t)N * 16 * 4;                 // 6.4 MB
    size_t szN16h = (size_t)N * 16 * 2;                 // 3.2 MB
    size_t szN    = ((size_t)N * 4 + 15) & ~(size_t)15;
    size_t szEh   = ((size_t)E * 2 + 15) & ~(size_t)15; // 3.2 MB
    size_t szE4   = (size_t)E * 4;                      // 6.4 MB
    size_t szE16  = (size_t)E * 16;                     // 25.6 MB (eah)

    // ---- workspace (~97 MB; rounds 4/5 proved ws >= ~100 MB) ----
    size_t pos_off  = 0;
    size_t r_off    = pos_off  + szN;
    size_t p_off    = r_off    + szEh;
    size_t hws_off  = p_off    + szE4;
    size_t hwdh_off = hws_off  + szN16f;
    size_t eah_off  = hwdh_off + szN16h;
    size_t m2h_off  = eah_off  + szE16;
    // overlays inside m2h (dead before edge_mlp1 writes it):
    size_t deg_off  = m2h_off;
    size_t cs_off   = deg_off  + szN;
    size_t cf_off   = cs_off   + 4096;

    int*            pos  = (int*)  ((char*)d_ws + pos_off);
    unsigned short* r    = (unsigned short*)((char*)d_ws + r_off);
    int*            p    = (int*)  ((char*)d_ws + p_off);
    float*          hw_s = (float*)((char*)d_ws + hws_off);
    unsigned short* hwdh = (unsigned short*)((char*)d_ws + hwdh_off);
    _Float16*       eah  = (_Float16*)((char*)d_ws + eah_off);
    _Float16*       m2h  = (_Float16*)((char*)d_ws + m2h_off);
    int*            deg  = (int*)  ((char*)d_ws + deg_off);
    int*            csum = (int*)  ((char*)d_ws + cs_off);
    int*            coff = (int*)  ((char*)d_ws + cf_off);

    hipMemsetAsync(deg, 0, (size_t)N * 4, stream);
    rank_cvt<<<egrid, BLK, 0, stream>>>(ei, ea, deg, r, eah, E);
    scan_chunk_sums<<<nch, BLK, 0, stream>>>(deg, csum, N);
    scan_chunk_off<<<1, 64, 0, stream>>>(csum, coff, nch);
    scan_within_excl<<<nch, BLK, 0, stream>>>(deg, pos, coff, N);
    edge_mlp1<<<mgrid, BLK, 0, stream>>>(x, ei, eah, pos, r, p,
                                         c1_w1, c1_b1, c1_w2, c1_b2, m2h, E);
    segmax1_hw<<<ggrid, BLK, 0, stream>>>(m2h, pos, c2_w1, c2_b1,
                                          hw_s, hwdh, N, E);
    edge_mlp2<<<mgrid, BLK, 0, stream>>>(hw_s, hwdh, ei, eah, p,
                                         c2_w1, c2_w2, c2_b2, m2h, E);
    segmax2_head<<<ggrid, BLK, 0, stream>>>(m2h, pos, l1_w, l1_b, l2_w, l2_b,
                                            out, N, E);
}

// Round 11
// 377.187 us; speedup vs baseline: 1.2952x; 1.2952x over previous
//
#include <hip/hip_runtime.h>
#include <hip/hip_fp16.h>

#define CHUNK 1024

typedef _Float16 half8 __attribute__((ext_vector_type(8)));
typedef float floatx4 __attribute__((ext_vector_type(4)));
typedef unsigned int uintx4 __attribute__((ext_vector_type(4)));

__device__ __forceinline__ unsigned int pack2(float a, float b) {
    __half2 h = __floats2half2_rn(a, b);
    return *(unsigned int*)&h;
}
__device__ __forceinline__ float2 unpack2(unsigned int u) {
    __half2 h = *(__half2*)&u;
    return __half22float2(h);
}
__device__ __forceinline__ uintx4 nt_load16(const void* p) {
    return __builtin_nontemporal_load((const uintx4*)p);
}
__device__ __forceinline__ void nt_store16(void* p, half8 v) {
    __builtin_nontemporal_store(*(uintx4*)&v, (uintx4*)p);
}

// ===========================================================================
// rank + fp16-convert fused: r[e] = rank within src bucket (atomic histo),
// eah[e] = fp16(ea[e]). ea read / eah write are full-line streams -> nt safe.
// ===========================================================================
__global__ __launch_bounds__(256) void rank_cvt(
    const int* __restrict__ ei, const float* __restrict__ ea,
    int* __restrict__ deg, unsigned short* __restrict__ r,
    _Float16* __restrict__ eah, int E)
{
    int e = blockIdx.x * 256 + threadIdx.x;
    if (e >= E) return;
    r[e] = (unsigned short)atomicAdd(&deg[ei[e]], 1);
    uintx4 u0 = nt_load16(ea + (size_t)e * 8);
    uintx4 u1 = nt_load16(ea + (size_t)e * 8 + 4);
    float4 a0 = *(float4*)&u0;
    float4 a1 = *(float4*)&u1;
    half8 h;
    h[0] = (_Float16)a0.x; h[1] = (_Float16)a0.y;
    h[2] = (_Float16)a0.z; h[3] = (_Float16)a0.w;
    h[4] = (_Float16)a1.x; h[5] = (_Float16)a1.y;
    h[6] = (_Float16)a1.z; h[7] = (_Float16)a1.w;
    nt_store16(eah + (size_t)e * 8, h);
}

__global__ __launch_bounds__(256) void scan_chunk_sums(
    const int* __restrict__ v, int* __restrict__ csum, int N)
{
    __shared__ int s[256];
    int base = blockIdx.x * CHUNK;
    int t = threadIdx.x;
    int acc = 0;
    #pragma unroll
    for (int i = 0; i < CHUNK / 256; ++i) {
        int idx = base + t + i * 256;
        if (idx < N) acc += v[idx];
    }
    s[t] = acc; __syncthreads();
    for (int o = 128; o > 0; o >>= 1) {
        if (t < o) s[t] += s[t + o];
        __syncthreads();
    }
    if (t == 0) csum[blockIdx.x] = s[0];
}

__global__ void scan_chunk_off(
    const int* __restrict__ csum, int* __restrict__ coff, int nch)
{
    if (threadIdx.x == 0 && blockIdx.x == 0) {
        int acc = 0;
        for (int i = 0; i < nch; ++i) { coff[i] = acc; acc += csum[i]; }
    }
}

__global__ __launch_bounds__(256) void scan_within_excl(
    const int* __restrict__ deg, int* __restrict__ pos,
    const int* __restrict__ coff, int N)
{
    __shared__ int s[256];
    int t = threadIdx.x;
    int base = blockIdx.x * CHUNK + t * 4;
    int v0 = 0, v1 = 0, v2 = 0, v3 = 0;
    if (base + 0 < N) v0 = deg[base + 0];
    if (base + 1 < N) v1 = deg[base + 1];
    if (base + 2 < N) v2 = deg[base + 2];
    if (base + 3 < N) v3 = deg[base + 3];
    s[t] = v0 + v1 + v2 + v3;
    __syncthreads();
    for (int o = 1; o < 256; o <<= 1) {
        int add = (t >= o) ? s[t - o] : 0;
        __syncthreads();
        s[t] += add;
        __syncthreads();
    }
    int run = coff[blockIdx.x] + (t > 0 ? s[t - 1] : 0);
    if (base + 0 < N) pos[base + 0] = run; run += v0;
    if (base + 1 < N) pos[base + 1] = run; run += v1;
    if (base + 2 < N) pos[base + 2] = run; run += v2;
    if (base + 3 < N) pos[base + 3] = run;
}

// ===========================================================================
// MFMA edge-MLP: one 64-edge macro-tile per wave; scattered output stores
// are REGULAR (L2 write-combines them — R10 proved nt causes HBM RMW) and
// PAIR-COALESCED: lanes 2i/2i+1 store edge-i's two 16 B halves at contiguous
// addresses -> wave coalescer emits 32 B transactions (half the scattered
// transaction count of per-lane row stores).
//   16x16x32 layouts: A[m=lane&15][k=8q+j], B[k=8q+j][n=lane&15],
//   C/D: col=lane&15, row=4q+reg.
// ===========================================================================
__global__ __launch_bounds__(256) void edge_mlp1(
    const float* __restrict__ x,          // [N,4]
    const int*   __restrict__ ei,         // [2,E]
    const _Float16* __restrict__ eah,     // [E,8] fp16
    const int*   __restrict__ pos,
    const unsigned short* __restrict__ r,
    int* __restrict__ pout,               // [E] CSR slot per edge (for mlp2)
    const float* __restrict__ w1, const float* __restrict__ b1,  // 16x16
    const float* __restrict__ w2, const float* __restrict__ b2,  // 16x16
    _Float16* __restrict__ m2h,           // [E,16] CSR-ordered
    int E)
{
    __shared__ _Float16 itm[4][4][16][24];   // [wave][tile][edge-row][ch+pad]
    int tid = threadIdx.x;
    int w = tid >> 6, lane = tid & 63;
    int e16 = lane & 15, q = lane >> 4;
    int ntiles = (E + 63) >> 6;
    int tile = blockIdx.x * 4 + w;
    if (tile >= ntiles) return;
    int ebase = tile << 6;
    int e = ebase + lane;

    int s_l = 0, d_l = 0, p_l = 0;
    if (e < E) {
        s_l = ei[e];
        d_l = ei[E + e];
        p_l = pos[s_l] + (int)r[e];
        __builtin_nontemporal_store(p_l, pout + e);
    }

    half8 B1, B2;
    #pragma unroll
    for (int j = 0; j < 8; ++j) { B1[j] = (_Float16)0.f; B2[j] = (_Float16)0.f; }
    if (q < 2) {
        #pragma unroll
        for (int j = 0; j < 8; ++j) {
            B1[j] = (_Float16)w1[(8 * q + j) * 16 + e16];
            B2[j] = (_Float16)w2[(8 * q + j) * 16 + e16];
        }
    }
    float b1c = b1[e16], b2c = b2[e16];

    half8 A[4];
    #pragma unroll
    for (int t = 0; t < 4; ++t) {
        int st = __shfl(s_l, 16 * t + e16, 64);
        int dt = __shfl(d_l, 16 * t + e16, 64);
        half8 a;
        #pragma unroll
        for (int j = 0; j < 8; ++j) a[j] = (_Float16)0.f;
        int et = ebase + 16 * t + e16;
        if (q == 0 && et < E) {
            float4 xs = *(const float4*)(x + (size_t)st * 4);
            float4 xd = *(const float4*)(x + (size_t)dt * 4);
            a[0] = (_Float16)xs.x; a[1] = (_Float16)xs.y;
            a[2] = (_Float16)xs.z; a[3] = (_Float16)xs.w;
            a[4] = (_Float16)xd.x; a[5] = (_Float16)xd.y;
            a[6] = (_Float16)xd.z; a[7] = (_Float16)xd.w;
        } else if (q == 1 && et < E) {
            a = *(const half8*)(eah + (size_t)et * 8);
        }
        A[t] = a;
    }

    floatx4 C[4];
    #pragma unroll
    for (int t = 0; t < 4; ++t) {
        floatx4 c = {b1c, b1c, b1c, b1c};
        C[t] = __builtin_amdgcn_mfma_f32_16x16x32_f16(A[t], B1, c, 0, 0, 0);
    }
    #pragma unroll
    for (int t = 0; t < 4; ++t)
        #pragma unroll
        for (int i = 0; i < 4; ++i)
            itm[w][t][4 * q + i][e16] = (_Float16)fmaxf(C[t][i], 0.0f);
    __builtin_amdgcn_wave_barrier();

    half8 A2[4];
    #pragma unroll
    for (int t = 0; t < 4; ++t) {
        half8 a;
        #pragma unroll
        for (int j = 0; j < 8; ++j) a[j] = (_Float16)0.f;
        if (q < 2) a = *(const half8*)&itm[w][t][e16][8 * q];
        A2[t] = a;
    }
    __builtin_amdgcn_wave_barrier();
    floatx4 C2[4];
    #pragma unroll
    for (int t = 0; t < 4; ++t) {
        floatx4 c = {b2c, b2c, b2c, b2c};
        C2[t] = __builtin_amdgcn_mfma_f32_16x16x32_f16(A2[t], B2, c, 0, 0, 0);
    }
    #pragma unroll
    for (int t = 0; t < 4; ++t)
        #pragma unroll
        for (int i = 0; i < 4; ++i)
            itm[w][t][4 * q + i][e16] = (_Float16)C2[t][i];
    __builtin_amdgcn_wave_barrier();

    // pair-coalesced scatter: lanes (2i,2i+1) store halves of edge i
    #pragma unroll
    for (int half = 0; half < 2; ++half) {
        int eloc = (lane >> 1) + 32 * half;       // edge-in-tile 0..63
        int pp = __shfl(p_l, eloc, 64);
        half8 v = *(const half8*)&itm[w][eloc >> 4][eloc & 15][8 * (lane & 1)];
        if (ebase + eloc < E)
            *(half8*)(m2h + (size_t)pp * 16 + 8 * (lane & 1)) = v;
    }
}

__global__ __launch_bounds__(256) void edge_mlp2(
    const float* __restrict__ hw_s,            // [N,16] fp32 (cb1 folded)
    const unsigned short* __restrict__ hw_dh,  // [N,16] fp16
    const int*   __restrict__ ei,
    const _Float16* __restrict__ eah,
    const int*   __restrict__ p,               // [E] precomputed CSR slots
    const float* __restrict__ w1,              // [40,16] rows 32:40 used
    const float* __restrict__ w2, const float* __restrict__ b2,
    _Float16* __restrict__ m2h, int E)
{
    __shared__ _Float16 itm[4][4][16][24];
    int tid = threadIdx.x;
    int w = tid >> 6, lane = tid & 63;
    int e16 = lane & 15, q = lane >> 4;
    const __half* hwd = (const __half*)hw_dh;
    int ntiles = (E + 63) >> 6;
    int tile = blockIdx.x * 4 + w;
    if (tile >= ntiles) return;
    int ebase = tile << 6;
    int e = ebase + lane;

    int s_l = 0, d_l = 0, p_l = 0;
    if (e < E) {
        s_l = ei[e];
        d_l = ei[E + e];
        p_l = p[e];
    }

    half8 B1, B2;
    #pragma unroll
    for (int j = 0; j < 8; ++j) { B1[j] = (_Float16)0.f; B2[j] = (_Float16)0.f; }
    if (q == 0) {
        #pragma unroll
        for (int j = 0; j < 8; ++j)
            B1[j] = (_Float16)w1[(32 + j) * 16 + e16];
    }
    if (q < 2) {
        #pragma unroll
        for (int j = 0; j < 8; ++j)
            B2[j] = (_Float16)w2[(8 * q + j) * 16 + e16];
    }
    float b2c = b2[e16];

    half8 A[4];
    #pragma unroll
    for (int t = 0; t < 4; ++t) {
        half8 a;
        #pragma unroll
        for (int j = 0; j < 8; ++j) a[j] = (_Float16)0.f;
        int et = ebase + 16 * t + e16;
        if (q == 0 && et < E)
            a = *(const half8*)(eah + (size_t)et * 8);
        A[t] = a;
    }

    floatx4 C[4];
    #pragma unroll
    for (int t = 0; t < 4; ++t) {
        floatx4 c;
        #pragma unroll
        for (int i = 0; i < 4; ++i) {
            int li = 16 * t + 4 * q + i;
            int s = __shfl(s_l, li, 64);
            int d = __shfl(d_l, li, 64);
            int rr = ebase + li;
            float v = 0.0f;
            if (rr < E) {
                v = hw_s[(size_t)s * 16 + e16]
                  + __half2float(hwd[(size_t)d * 16 + e16]);
            }
            c[i] = v;
        }
        C[t] = __builtin_amdgcn_mfma_f32_16x16x32_f16(A[t], B1, c, 0, 0, 0);
    }
    #pragma unroll
    for (int t = 0; t < 4; ++t)
        #pragma unroll
        for (int i = 0; i < 4; ++i)
            itm[w][t][4 * q + i][e16] = (_Float16)fmaxf(C[t][i], 0.0f);
    __builtin_amdgcn_wave_barrier();

    half8 A2[4];
    #pragma unroll
    for (int t = 0; t < 4; ++t) {
        half8 a;
        #pragma unroll
        for (int j = 0; j < 8; ++j) a[j] = (_Float16)0.f;
        if (q < 2) a = *(const half8*)&itm[w][t][e16][8 * q];
        A2[t] = a;
    }
    __builtin_amdgcn_wave_barrier();
    floatx4 C2[4];
    #pragma unroll
    for (int t = 0; t < 4; ++t) {
        floatx4 c = {b2c, b2c, b2c, b2c};
        C2[t] = __builtin_amdgcn_mfma_f32_16x16x32_f16(A2[t], B2, c, 0, 0, 0);
    }
    #pragma unroll
    for (int t = 0; t < 4; ++t)
        #pragma unroll
        for (int i = 0; i < 4; ++i)
            itm[w][t][4 * q + i][e16] = (_Float16)C2[t][i];
    __builtin_amdgcn_wave_barrier();

    #pragma unroll
    for (int half = 0; half < 2; ++half) {
        int eloc = (lane >> 1) + 32 * half;
        int pp = __shfl(p_l, eloc, 64);
        half8 v = *(const half8*)&itm[w][eloc >> 4][eloc & 15][8 * (lane & 1)];
        if (ebase + eloc < E)
            *(half8*)(m2h + (size_t)pp * 16 + 8 * (lane & 1)) = v;
    }
}

// ===========================================================================
// Streaming segment-max kernels (8 lanes/node) + fused epilogues.
// m2h reads are non-temporal (single-use stream).
// ===========================================================================
__global__ __launch_bounds__(256) void segmax1_hw(
    const _Float16* __restrict__ m2h, const int* __restrict__ pos,
    const float* __restrict__ cw1, const float* __restrict__ cb1,
    float* __restrict__ hw_s, unsigned short* __restrict__ hw_dh,
    int N, int E)
{
    int tid = threadIdx.x;
    int n = blockIdx.x * 32 + (tid >> 3);
    if (n >= N) return;
    int g = tid & 7;
    int start = pos[n];
    int end = (n + 1 < N) ? pos[n + 1] : E;

    float acc[16];
    #pragma unroll
    for (int j = 0; j < 16; ++j) acc[j] = 0.0f;

    for (int k = start + g; k < end; k += 8) {
        uintx4 u0 = nt_load16(m2h + (size_t)k * 16);
        uintx4 u1 = nt_load16(m2h + (size_t)k * 16 + 8);
        float2 f;
        f = unpack2(u0.x); acc[0]  = fmaxf(acc[0],  f.x); acc[1]  = fmaxf(acc[1],  f.y);
        f = unpack2(u0.y); acc[2]  = fmaxf(acc[2],  f.x); acc[3]  = fmaxf(acc[3],  f.y);
        f = unpack2(u0.z); acc[4]  = fmaxf(acc[4],  f.x); acc[5]  = fmaxf(acc[5],  f.y);
        f = unpack2(u0.w); acc[6]  = fmaxf(acc[6],  f.x); acc[7]  = fmaxf(acc[7],  f.y);
        f = unpack2(u1.x); acc[8]  = fmaxf(acc[8],  f.x); acc[9]  = fmaxf(acc[9],  f.y);
        f = unpack2(u1.y); acc[10] = fmaxf(acc[10], f.x); acc[11] = fmaxf(acc[11], f.y);
        f = unpack2(u1.z); acc[12] = fmaxf(acc[12], f.x); acc[13] = fmaxf(acc[13], f.y);
        f = unpack2(u1.w); acc[14] = fmaxf(acc[14], f.x); acc[15] = fmaxf(acc[15], f.y);
    }
    #pragma unroll
    for (int mask = 1; mask < 8; mask <<= 1) {
        #pragma unroll
        for (int j = 0; j < 16; ++j)
            acc[j] = fmaxf(acc[j], __shfl_xor(acc[j], mask, 64));
    }

    int j0 = 2 * g, j1 = 2 * g + 1;
    float hs0 = cb1[j0], hs1 = cb1[j1], hd0 = 0.0f, hd1 = 0.0f;
    #pragma unroll
    for (int k = 0; k < 16; ++k) {
        float ak = acc[k];
        hs0 = fmaf(ak, cw1[k * 16 + j0], hs0);
        hs1 = fmaf(ak, cw1[k * 16 + j1], hs1);
        hd0 = fmaf(ak, cw1[(16 + k) * 16 + j0], hd0);
        hd1 = fmaf(ak, cw1[(16 + k) * 16 + j1], hd1);
    }
    *(float2*)(hw_s + (size_t)n * 16 + j0) = make_float2(hs0, hs1);
    ((unsigned int*)hw_dh)[(size_t)n * 8 + g] = pack2(hd0, hd1);
}

__global__ __launch_bounds__(256) void segmax2_head(
    const _Float16* __restrict__ m2h, const int* __restrict__ pos,
    const float* __restrict__ l1w, const float* __restrict__ l1b,
    const float* __restrict__ l2w, const float* __restrict__ l2b,
    float* __restrict__ out, int N, int E)
{
    int tid = threadIdx.x;
    int n = blockIdx.x * 32 + (tid >> 3);
    if (n >= N) return;
    int g = tid & 7;
    int start = pos[n];
    int end = (n + 1 < N) ? pos[n + 1] : E;

    float acc[16];
    #pragma unroll
    for (int j = 0; j < 16; ++j) acc[j] = 0.0f;

    for (int k = start + g; k < end; k += 8) {
        uintx4 u0 = nt_load16(m2h + (size_t)k * 16);
        uintx4 u1 = nt_load16(m2h + (size_t)k * 16 + 8);
        float2 f;
        f = unpack2(u0.x); acc[0]  = fmaxf(acc[0],  f.x); acc[1]  = fmaxf(acc[1],  f.y);
        f = unpack2(u0.y); acc[2]  = fmaxf(acc[2],  f.x); acc[3]  = fmaxf(acc[3],  f.y);
        f = unpack2(u0.z); acc[4]  = fmaxf(acc[4],  f.x); acc[5]  = fmaxf(acc[5],  f.y);
        f = unpack2(u0.w); acc[6]  = fmaxf(acc[6],  f.x); acc[7]  = fmaxf(acc[7],  f.y);
        f = unpack2(u1.x); acc[8]  = fmaxf(acc[8],  f.x); acc[9]  = fmaxf(acc[9],  f.y);
        f = unpack2(u1.y); acc[10] = fmaxf(acc[10], f.x); acc[11] = fmaxf(acc[11], f.y);
        f = unpack2(u1.z); acc[12] = fmaxf(acc[12], f.x); acc[13] = fmaxf(acc[13], f.y);
        f = unpack2(u1.w); acc[14] = fmaxf(acc[14], f.x); acc[15] = fmaxf(acc[15], f.y);
    }
    #pragma unroll
    for (int mask = 1; mask < 8; mask <<= 1) {
        #pragma unroll
        for (int j = 0; j < 16; ++j)
            acc[j] = fmaxf(acc[j], __shfl_xor(acc[j], mask, 64));
    }

    float t2[16];
    #pragma unroll
    for (int j = 0; j < 16; ++j) t2[j] = l1b[j];
    #pragma unroll
    for (int kk = 0; kk < 16; ++kk) {
        float ak = acc[kk];
        #pragma unroll
        for (int j = 0; j < 16; ++j) t2[j] = fmaf(ak, l1w[kk * 16 + j], t2[j]);
    }
    float r2 = l2b[0];
    #pragma unroll
    for (int j = 0; j < 16; ++j) r2 = fmaf(fmaxf(t2[j], 0.0f), l2w[j], r2);
    if (g == 0) out[n] = r2;
}

// ===========================================================================
extern "C" void kernel_launch(void* const* d_in, const int* in_sizes, int n_in,
                              void* d_out, int out_size, void* d_ws, size_t ws_size,
                              hipStream_t stream)
{
    const float* x     = (const float*)d_in[0];
    const int*   ei    = (const int*)  d_in[1];
    const float* ea    = (const float*)d_in[2];
    const float* c1_w1 = (const float*)d_in[3];
    const float* c1_b1 = (const float*)d_in[4];
    const float* c1_w2 = (const float*)d_in[5];
    const float* c1_b2 = (const float*)d_in[6];
    const float* c2_w1 = (const float*)d_in[7];
    const float* c2_b1 = (const float*)d_in[8];
    const float* c2_w2 = (const float*)d_in[9];
    const float* c2_b2 = (const float*)d_in[10];
    const float* l1_w  = (const float*)d_in[11];
    const float* l1_b  = (const float*)d_in[12];
    const float* l2_w  = (const float*)d_in[13];
    const float* l2_b  = (const float*)d_in[14];
    float* out = (float*)d_out;

    const int N = in_sizes[0] / 4;   // 100000
    const int E = in_sizes[2] / 8;   // 1600000
    const int nch = (N + CHUNK - 1) / CHUNK;

    const int BLK = 256;
    const int egrid = (E + BLK - 1) / BLK;
    const int ggrid = (N + 31) / 32;
    const int ntiles64 = (E + 63) >> 6;
    const int mgrid = (ntiles64 + 3) / 4;     // one 64-edge tile per wave

    size_t szN16f = (size_t)N * 16 * 4;                 // 6.4 MB
    size_t szN16h = (size_t)N * 16 * 2;                 // 3.2 MB
    size_t szN    = ((size_t)N * 4 + 15) & ~(size_t)15;
    size_t szEh   = ((size_t)E * 2 + 15) & ~(size_t)15; // 3.2 MB
    size_t szE4   = (size_t)E * 4;                      // 6.4 MB
    size_t szE16  = (size_t)E * 16;                     // 25.6 MB (eah)

    // ---- workspace (~97 MB) ----
    size_t pos_off  = 0;
    size_t r_off    = pos_off  + szN;
    size_t p_off    = r_off    + szEh;
    size_t hws_off  = p_off    + szE4;
    size_t hwdh_off = hws_off  + szN16f;
    size_t eah_off  = hwdh_off + szN16h;
    size_t m2h_off  = eah_off  + szE16;
    // overlays inside m2h (dead before edge_mlp1 writes it):
    size_t deg_off  = m2h_off;
    size_t cs_off   = deg_off  + szN;
    size_t cf_off   = cs_off   + 4096;

    int*            pos  = (int*)  ((char*)d_ws + pos_off);
    unsigned short* r    = (unsigned short*)((char*)d_ws + r_off);
    int*            p    = (int*)  ((char*)d_ws + p_off);
    float*          hw_s = (float*)((char*)d_ws + hws_off);
    unsigned short* hwdh = (unsigned short*)((char*)d_ws + hwdh_off);
    _Float16*       eah  = (_Float16*)((char*)d_ws + eah_off);
    _Float16*       m2h  = (_Float16*)((char*)d_ws + m2h_off);
    int*            deg  = (int*)  ((char*)d_ws + deg_off);
    int*            csum = (int*)  ((char*)d_ws + cs_off);
    int*            coff = (int*)  ((char*)d_ws + cf_off);

    hipMemsetAsync(deg, 0, (size_t)N * 4, stream);
    rank_cvt<<<egrid, BLK, 0, stream>>>(ei, ea, deg, r, eah, E);
    scan_chunk_sums<<<nch, BLK, 0, stream>>>(deg, csum, N);
    scan_chunk_off<<<1, 64, 0, stream>>>(csum, coff, nch);
    scan_within_excl<<<nch, BLK, 0, stream>>>(deg, pos, coff, N);
    edge_mlp1<<<mgrid, BLK, 0, stream>>>(x, ei, eah, pos, r, p,
                                         c1_w1, c1_b1, c1_w2, c1_b2, m2h, E);
    segmax1_hw<<<ggrid, BLK, 0, stream>>>(m2h, pos, c2_w1, c2_b1,
                                          hw_s, hwdh, N, E);
    edge_mlp2<<<mgrid, BLK, 0, stream>>>(hw_s, hwdh, ei, eah, p,
                                         c2_w1, c2_w2, c2_b2, m2h, E);
    segmax2_head<<<ggrid, BLK, 0, stream>>>(m2h, pos, l1_w, l1_b, l2_w, l2_b,
                                            out, N, E);
}